// Round 11
// baseline (127.186 us; speedup 1.0000x reference)
//
#include <hip/hip_runtime.h>
#include <hip/hip_bf16.h>

// MultiHeadAttention: x(2,2048,1024) fp32 -> out(2,2048,1024) fp32
// Pipeline: fused cvt->bf16; QKV GEMM (LDS-staged mfma) -> q(*0.125*log2e),k,v^T;
// flash attn split over 2 KV halves (4 waves x 32 q-rows, swapped QK^T, in-reg P,
// deferred max) -> bf16 partials + (m,l); merge; out GEMM.
//
// ws layout (43MB):
//   [0,8M)    xb (bf16 x)  -> P0 partial -> merged attn-out
//   [8,16M)   wqkv (6MB)   -> P1 partial (8MB)
//   [16,24M)  q
//   [24,32M)  k
//   [32,40M)  vt
//   [40,42M)  wout
//   [42,42.5M) M[2][32][2048] f32 ; [42.5,43M) L[2][32][2048] f32

typedef __bf16 bf16x8 __attribute__((ext_vector_type(8)));
typedef __bf16 bf16x4 __attribute__((ext_vector_type(4)));
typedef short short4v __attribute__((ext_vector_type(4)));
typedef float f32x4 __attribute__((ext_vector_type(4)));

#define QSCALE 0.18033688011112042f  // 0.125 * log2(e): QK^T lands in log2 domain

__device__ __forceinline__ unsigned short bfbits(float f) {
    union { __bf16 h; unsigned short u; } cv;
    cv.h = (__bf16)f;
    return cv.u;
}

__device__ __forceinline__ float bf2f(unsigned short u) {
    union { unsigned int i; float f; } v;
    v.i = ((unsigned int)u) << 16;
    return v.f;
}

__device__ __forceinline__ f32x4 mfma16(bf16x4 a, bf16x4 b, f32x4 c) {
#if __has_builtin(__builtin_amdgcn_mfma_f32_16x16x16bf16_1k)
    union { bf16x4 h; short4v s; } ua, ub;
    ua.h = a; ub.h = b;
    return __builtin_amdgcn_mfma_f32_16x16x16bf16_1k(ua.s, ub.s, c, 0, 0, 0);
#else
    f32x4 d = c;
    asm volatile("v_mfma_f32_16x16x16_bf16 %0, %1, %2, %0"
                 : "+v"(d) : "v"(a), "v"(b));
    return d;
#endif
}

__device__ __forceinline__ void gl_lds16(const void* g, void* l) {
    __builtin_amdgcn_global_load_lds(
        (__attribute__((address_space(1))) const unsigned int*)g,
        (__attribute__((address_space(3))) unsigned int*)l, 16, 0, 0);
}

// Fused bf16 conversion into three regions.
__global__ void cvt_all(const float4* __restrict__ x,
                        const float4* __restrict__ wq,
                        const float4* __restrict__ wo,
                        ushort4* __restrict__ d0,
                        ushort4* __restrict__ d1,
                        ushort4* __restrict__ d2) {
    int i = blockIdx.x * blockDim.x + threadIdx.x;
    const int stride = gridDim.x * blockDim.x;
    for (; i < 2097152; i += stride) {
        float4 f;
        ushort4* d;
        int k;
        if (i < 1048576)       { f = x[i];           d = d0; k = i; }
        else if (i < 1835008)  { f = wq[i - 1048576]; d = d1; k = i - 1048576; }
        else                   { f = wo[i - 1835008]; d = d2; k = i - 1835008; }
        ushort4 o;
        o.x = bfbits(f.x); o.y = bfbits(f.y); o.z = bfbits(f.z); o.w = bfbits(f.w);
        d[k] = o;
    }
}

// C = A(M x 1024) @ W(N x 1024)^T + bias. 128x128 block tile, 4 waves (2x2) of 64x64.
// m97 structure: BK=64 single-buffer LDS, global_load_lds w16 staging, 2-barrier K-loop.
// MODE 0: N=3072, scatter to q (scaled QSCALE), k, vt (v transposed [bh][dk][n]) as bf16.
// MODE 1: N=1024, fp32 out row-major.
template<int MODE>
__global__ __launch_bounds__(256, 3) void gemm_mfma(
    const unsigned short* __restrict__ A,
    const unsigned short* __restrict__ W,
    const float* __restrict__ bias,
    unsigned short* __restrict__ qo,
    unsigned short* __restrict__ ko,
    unsigned short* __restrict__ vto,
    float* __restrict__ fo) {
    __shared__ __attribute__((aligned(128))) unsigned char smem[32768];
    const int lane = threadIdx.x & 63;
    const int w = threadIdx.x >> 6;
    const int g = lane >> 4, c = lane & 15;
    const int wr = w >> 1, wc = w & 1;
    const int row0 = blockIdx.x * 128;
    const int col0 = blockIdx.y * 128;

    const int rloc = lane >> 3;                      // 0..7
    const int csrc = ((lane & 7) ^ rloc) * 8;        // pre-swizzled source chunk (elements)

    f32x4 acc[4][4] = {};

    for (int kt = 0; kt < 1024; kt += 64) {
        #pragma unroll
        for (int i = 0; i < 4; ++i) {
            const int r = i * 32 + w * 8 + rloc;
            gl_lds16(A + (size_t)(row0 + r) * 1024 + kt + csrc,
                     smem + i * 4096 + w * 1024);
            gl_lds16(W + (size_t)(col0 + r) * 1024 + kt + csrc,
                     smem + 16384 + i * 4096 + w * 1024);
        }
        __syncthreads();

        #pragma unroll
        for (int ks = 0; ks < 2; ++ks) {
            bf16x8 a[4], b[4];
            #pragma unroll
            for (int mi = 0; mi < 4; ++mi) {
                const int r = wr * 64 + mi * 16 + c;
                a[mi] = *(const bf16x8*)(smem + r * 128 + (((ks * 4 + g) ^ (r & 7)) * 16));
            }
            #pragma unroll
            for (int ni = 0; ni < 4; ++ni) {
                const int r = wc * 64 + ni * 16 + c;
                b[ni] = *(const bf16x8*)(smem + 16384 + r * 128 + (((ks * 4 + g) ^ (r & 7)) * 16));
            }
            #pragma unroll
            for (int mi = 0; mi < 4; ++mi)
                #pragma unroll
                for (int ni = 0; ni < 4; ++ni)
                    acc[mi][ni] = __builtin_amdgcn_mfma_f32_16x16x32_bf16(
                        a[mi], b[ni], acc[mi][ni], 0, 0, 0);
        }
        __syncthreads();
    }

    #pragma unroll
    for (int mi = 0; mi < 4; ++mi) {
        #pragma unroll
        for (int ni = 0; ni < 4; ++ni) {
            const int col = col0 + wc * 64 + ni * 16 + c;
            const float bv = bias[col];
            #pragma unroll
            for (int j = 0; j < 4; ++j) {
                const int row = row0 + wr * 64 + mi * 16 + 4 * g + j;
                float v = acc[mi][ni][j] + bv;
                if (MODE == 1) {
                    fo[(size_t)row * 1024 + col] = v;
                } else {
                    const int sec = col >> 10;          // 0=q 1=k 2=v
                    const int d = col & 1023;
                    const int h = d >> 6, dk = d & 63;
                    const int b_ = row >> 11, n = row & 2047;
                    const int bh = b_ * 16 + h;
                    if (sec == 0)
                        qo[((size_t)(bh * 2048 + n) << 6) + dk] = bfbits(v * QSCALE);
                    else if (sec == 1)
                        ko[((size_t)(bh * 2048 + n) << 6) + dk] = bfbits(v);
                    else
                        vto[(size_t)(bh * 64 + dk) * 2048 + n] = bfbits(v);
                }
            }
        }
    }
}

// Flash attention over one KV half (blockIdx.z selects half; 16 kv-tiles of 64).
// 4 waves x 32 q-rows (two 16-row groups a/b sharing every K/V LDS read).
// Swapped QK^T keeps P in-register (16x16x16 A-frag layout); log2-domain,
// deferred per-lane max. Emits normalized bf16 partial O + per-row (m, l).
// Q,K: [32][2048][64] bf16 (Q pre-scaled by QSCALE). Vt: [32][64][2048] bf16.
// Grid (16,32,2), 256 threads. LDS: K dbuf [0,16K), V dbuf [16K,32K).
__global__ __launch_bounds__(256, 4) void attn_flash(
    const unsigned short* __restrict__ Q,
    const unsigned short* __restrict__ K,
    const unsigned short* __restrict__ Vt,
    unsigned short* __restrict__ Pout,   // [2][4096][1024] bf16 (halves 8MB apart)
    float* __restrict__ Mb,              // [2][32][2048]
    float* __restrict__ Lb) {            // [2][32][2048]
    __shared__ __attribute__((aligned(128))) unsigned char smem[32768];
    const int lane = threadIdx.x & 63;
    const int w = threadIdx.x >> 6;          // 0..3
    const int g = lane >> 4, c = lane & 15;
    const int c7 = c & 7;
    const int bh = blockIdx.y;
    const int hz = blockIdx.z;               // KV half
    const int q0 = blockIdx.x * 128 + w * 32;
    const unsigned short* Qb = Q + (size_t)bh * 2048 * 64;
    const unsigned short* Kb = K + (size_t)bh * 2048 * 64;
    const unsigned short* Vb = Vt + (size_t)bh * 64 * 2048;

    const int rloc = lane >> 3;
    const int csrc = ((lane & 7) ^ (rloc & 7)) * 8;

    const int chunkKV0 = ((0 + g) ^ c7) * 16;
    const int chunkKV1 = ((4 + g) ^ c7) * 16;
    const int ghalf = g >> 1;
    const int gsub = (g & 1) * 8;

    bf16x8 aq[2][2];                          // [group][ks]
    #pragma unroll
    for (int qg = 0; qg < 2; ++qg)
        #pragma unroll
        for (int ks = 0; ks < 2; ++ks)
            aq[qg][ks] = *(const bf16x8*)(Qb + (size_t)(q0 + qg * 16 + c) * 64 + ks * 32 + 8 * g);

    f32x4 oa[4] = {}, ob[4] = {};
    f32x4 la = {}, lb = {};
    float ma = -1e30f, mb = -1e30f;

    bf16x4 ones4;
    #pragma unroll
    for (int i = 0; i < 4; ++i) ones4[i] = (__bf16)1.0f;

    const int gt0 = hz * 16;                  // first kv tile of this half

    // prologue: stage tile gt0 into buffer 0 (2 K + 2 V instrs per wave)
    #pragma unroll
    for (int tt = 0; tt < 2; ++tt) {
        const int t = 2 * w + tt;
        const int row = 8 * t + rloc;
        gl_lds16(Kb + (size_t)(gt0 * 64 + row) * 64 + csrc, smem + t * 1024);
        gl_lds16(Vb + (size_t)row * 2048 + gt0 * 64 + csrc, smem + 16384 + t * 1024);
    }
    __syncthreads();

    for (int t = 0; t < 16; ++t) {
        const int cur = t & 1;
        if (t + 1 < 16) {
            const int nb = cur ^ 1;
            const int gt = gt0 + t + 1;
            #pragma unroll
            for (int tt = 0; tt < 2; ++tt) {
                const int ti = 2 * w + tt;
                const int row = 8 * ti + rloc;
                gl_lds16(Kb + (size_t)(gt * 64 + row) * 64 + csrc,
                         smem + nb * 8192 + ti * 1024);
                gl_lds16(Vb + (size_t)row * 2048 + gt * 64 + csrc,
                         smem + 16384 + nb * 8192 + ti * 1024);
            }
        }

        const unsigned char* Kt = smem + cur * 8192;
        const unsigned char* Vtb = smem + 16384 + cur * 8192;

        // swapped QK^T for both groups; each K b128 read feeds 4 MFMAs
        f32x4 sa[4] = {}, sb[4] = {};
        __builtin_amdgcn_s_setprio(1);
        #pragma unroll
        for (int nj = 0; nj < 4; ++nj) {
            bf16x8 bk0 = *(const bf16x8*)(Kt + nj * 2048 + c * 128 + chunkKV0);
            bf16x8 bk1 = *(const bf16x8*)(Kt + nj * 2048 + c * 128 + chunkKV1);
            sa[nj] = __builtin_amdgcn_mfma_f32_16x16x32_bf16(bk0, aq[0][0], sa[nj], 0, 0, 0);
            sa[nj] = __builtin_amdgcn_mfma_f32_16x16x32_bf16(bk1, aq[0][1], sa[nj], 0, 0, 0);
            sb[nj] = __builtin_amdgcn_mfma_f32_16x16x32_bf16(bk0, aq[1][0], sb[nj], 0, 0, 0);
            sb[nj] = __builtin_amdgcn_mfma_f32_16x16x32_bf16(bk1, aq[1][1], sb[nj], 0, 0, 0);
        }
        __builtin_amdgcn_s_setprio(0);

        // per-lane partial maxes
        float pa = sa[0][0], pb = sb[0][0];
        #pragma unroll
        for (int nj = 0; nj < 4; ++nj)
            #pragma unroll
            for (int j = 0; j < 4; ++j) {
                pa = fmaxf(pa, sa[nj][j]);
                pb = fmaxf(pb, sb[nj][j]);
            }

        // deferred max: full reduce + rescale only on growth > 8 (log2 units)
        const bool trig = (pa > ma + 8.f) || (pb > mb + 8.f);
        if (__any((int)trig)) {
            float rm = pa;
            rm = fmaxf(rm, __shfl_xor(rm, 16));
            rm = fmaxf(rm, __shfl_xor(rm, 32));
            float mnew = fmaxf(ma, rm);
            float sc = __builtin_amdgcn_exp2f(ma - mnew);
            ma = mnew;
            #pragma unroll
            for (int j = 0; j < 4; ++j) {
                const float scj = __shfl(sc, 4 * g + j);
                la[j] *= scj;
                #pragma unroll
                for (int ni = 0; ni < 4; ++ni) oa[ni][j] *= scj;
            }
            rm = pb;
            rm = fmaxf(rm, __shfl_xor(rm, 16));
            rm = fmaxf(rm, __shfl_xor(rm, 32));
            mnew = fmaxf(mb, rm);
            sc = __builtin_amdgcn_exp2f(mb - mnew);
            mb = mnew;
            #pragma unroll
            for (int j = 0; j < 4; ++j) {
                const float scj = __shfl(sc, 4 * g + j);
                lb[j] *= scj;
                #pragma unroll
                for (int ni = 0; ni < 4; ++ni) ob[ni][j] *= scj;
            }
        }

        // P = 2^(s - m), packed directly as 16x16x16 A-fragments (k = 4g+j)
        bf16x4 qa_[4], qb_[4];
        #pragma unroll
        for (int nj = 0; nj < 4; ++nj)
            #pragma unroll
            for (int j = 0; j < 4; ++j) {
                qa_[nj][j] = (__bf16)__builtin_amdgcn_exp2f(sa[nj][j] - ma);
                qb_[nj][j] = (__bf16)__builtin_amdgcn_exp2f(sb[nj][j] - mb);
            }

        // PV: each V b64 read feeds both groups; ones-MFMA row sums
        f32x4 lta = {}, ltb = {};
        __builtin_amdgcn_s_setprio(1);
        #pragma unroll
        for (int nj = 0; nj < 4; ++nj) {
            lta = mfma16(qa_[nj], ones4, lta);
            ltb = mfma16(qb_[nj], ones4, ltb);
            #pragma unroll
            for (int ni = 0; ni < 4; ++ni) {
                bf16x4 bv = *(const bf16x4*)(Vtb + (ni * 16 + c) * 128 +
                                             (((2 * nj + ghalf) ^ c7) * 16) + gsub);
                oa[ni] = mfma16(qa_[nj], bv, oa[ni]);
                ob[ni] = mfma16(qb_[nj], bv, ob[ni]);
            }
        }
        __builtin_amdgcn_s_setprio(0);
        la += lta;
        lb += ltb;

        __syncthreads();
    }

    const int b_ = bh >> 4, h = bh & 15;
    unsigned short* Pp = Pout + (size_t)hz * 4194304;
    #pragma unroll
    for (int ni = 0; ni < 4; ++ni) {
        #pragma unroll
        for (int j = 0; j < 4; ++j) {
            const int col = h * 64 + ni * 16 + c;
            const int rowa = b_ * 2048 + q0 + 4 * g + j;
            Pp[(size_t)rowa * 1024 + col] = bfbits(oa[ni][j] / la[j]);
            Pp[(size_t)(rowa + 16) * 1024 + col] = bfbits(ob[ni][j] / lb[j]);
        }
    }
    const int mlbase = (hz * 32 + bh) * 2048 + q0;
    if (g == 0) {
        Mb[mlbase + c] = ma;
        Mb[mlbase + 16 + c] = mb;
    }
    if (c == 0) {
        #pragma unroll
        for (int j = 0; j < 4; ++j) {
            Lb[mlbase + 4 * g + j] = la[j];
            Lb[mlbase + 16 + 4 * g + j] = lb[j];
        }
    }
}

// Merge the two KV-half partials: O = (w0*P0 + w1*P1), w_h = l_h*2^(m_h-M) (normalized).
// In-place into the P0 region. 524288 threads x 8 elems.
__global__ __launch_bounds__(256) void attn_merge(const float* __restrict__ Mb,
                                                  const float* __restrict__ Lb,
                                                  unsigned short* __restrict__ P) {
    const unsigned tid = blockIdx.x * 256 + threadIdx.x;
    const unsigned base = tid * 8;
    const int r = base >> 10, col = base & 1023;
    const int bh = ((r >> 11) << 4) + (col >> 6);
    const int i0 = bh * 2048 + (r & 2047);
    const float m0 = Mb[i0], m1 = Mb[65536 + i0];
    const float l0 = Lb[i0], l1 = Lb[65536 + i0];
    const float mx = fmaxf(m0, m1);
    float w0 = l0 * __builtin_amdgcn_exp2f(m0 - mx);
    float w1 = l1 * __builtin_amdgcn_exp2f(m1 - mx);
    const float inv = 1.f / (w0 + w1);
    w0 *= inv; w1 *= inv;
    ushort4* p0 = (ushort4*)(P + (size_t)r * 1024 + col);
    const ushort4* p1 = (const ushort4*)(P + 4194304 + (size_t)r * 1024 + col);
    #pragma unroll
    for (int k = 0; k < 2; ++k) {
        ushort4 a = p0[k], b = p1[k], o;
        o.x = bfbits(w0 * bf2f(a.x) + w1 * bf2f(b.x));
        o.y = bfbits(w0 * bf2f(a.y) + w1 * bf2f(b.y));
        o.z = bfbits(w0 * bf2f(a.z) + w1 * bf2f(b.z));
        o.w = bfbits(w0 * bf2f(a.w) + w1 * bf2f(b.w));
        p0[k] = o;
    }
}

extern "C" void kernel_launch(void* const* d_in, const int* in_sizes, int n_in,
                              void* d_out, int out_size, void* d_ws, size_t ws_size,
                              hipStream_t stream) {
    const float* x     = (const float*)d_in[0];
    const float* qkv_w = (const float*)d_in[1];
    const float* qkv_b = (const float*)d_in[2];
    const float* out_w = (const float*)d_in[3];
    const float* out_b = (const float*)d_in[4];
    float* out = (float*)d_out;

    char* ws = (char*)d_ws;
    unsigned short* xb   = (unsigned short*)(ws);                //  8 MB: x bf16 -> P0 -> attn out
    unsigned short* wqkv = (unsigned short*)(ws + (8u  << 20));  //  6 MB -> P1 (8MB region)
    unsigned short* qb   = (unsigned short*)(ws + (16u << 20));  //  8 MB
    unsigned short* kb   = (unsigned short*)(ws + (24u << 20));  //  8 MB
    unsigned short* vtb  = (unsigned short*)(ws + (32u << 20));  //  8 MB
    unsigned short* wout = (unsigned short*)(ws + (40u << 20));  //  2 MB
    float* Mb = (float*)(ws + (42u << 20));                      // 512 KB
    float* Lb = (float*)(ws + (42u << 20) + (512u << 10));       // 512 KB

    cvt_all<<<2048, 256, 0, stream>>>((const float4*)x, (const float4*)qkv_w,
                                      (const float4*)out_w,
                                      (ushort4*)xb, (ushort4*)wqkv, (ushort4*)wout);

    gemm_mfma<0><<<dim3(32, 24), 256, 0, stream>>>(xb, wqkv, qkv_b, qb, kb, vtb, nullptr);

    unsigned short* part = xb;  // P0 at ws+0, P1 at ws+8M (wqkv region, free now)
    attn_flash<<<dim3(16, 32, 2), 256, 0, stream>>>(qb, kb, vtb, part, Mb, Lb);

    attn_merge<<<2048, 256, 0, stream>>>(Mb, Lb, part);

    gemm_mfma<1><<<dim3(32, 8), 256, 0, stream>>>(part, wout, out_b, nullptr, nullptr, nullptr, out);
}